// Round 6
// baseline (858.183 us; speedup 1.0000x reference)
//
#include <hip/hip_runtime.h>
#include <hip/hip_bf16.h>
#include <math.h>

namespace {

typedef __attribute__((ext_vector_type(8))) short  short8;
typedef __attribute__((ext_vector_type(4))) float  float4v;

constexpr float PI_F     = 3.14159265358979323846f;
constexpr float TWO_PI_F = 6.28318530717958647692f;

__device__ __forceinline__ unsigned pack2(float a, float b) {
    __hip_bfloat162 h = __float22bfloat162_rn(float2{a, b});
    unsigned r;
    __builtin_memcpy(&r, &h, 4);
    return r;
}

union Frag { unsigned u[4]; short8 s; };

__device__ __forceinline__ void gl2lds16(const void* g, void* l) {
    __builtin_amdgcn_global_load_lds(
        (const __attribute__((address_space(1))) void*)g,
        (__attribute__((address_space(3))) void*)l, 16, 0, 0);
}

// counted-vmcnt phase barrier: keep this phase's 2 stage-loads in flight,
// guarantee last phase's stage (older in FIFO) has landed. lgkmcnt(0) so no
// wave crosses with LDS reads of a soon-to-be-overwritten slot outstanding.
__device__ __forceinline__ void phase_barrier() {
    asm volatile("s_waitcnt vmcnt(2) lgkmcnt(0)" ::: "memory");
    __builtin_amdgcn_s_barrier();
    __builtin_amdgcn_sched_barrier(0);
}

// ---- prep: transpose + bf16 weights.
// W1T[d][n][k]   = W1[d][k][n]               (k < 128; k=128 handled as f32 rank-1)
// W2T[d][n][ks_] = W2[d][pi(ks_)][n], pi makes GEMM2's B-frag lane-local:
//   pi(kslot) = 32*(kslot>>5) + 16*((kslot>>2)&1) + 4*((kslot>>3)&3) + (kslot&3)
__global__ __launch_bounds__(256)
void prep_weights(const float* __restrict__ W1,
                  const float* __restrict__ W2,
                  ushort* __restrict__ W1T,
                  ushort* __restrict__ W2T) {
    const int idx = blockIdx.x * 256 + threadIdx.x;   // 0 .. 131071
    if (idx < 65536) {
        const int d = idx >> 14;
        const int n = (idx >> 7) & 127;
        const int k = idx & 127;
        __hip_bfloat16 v = __float2bfloat16(W1[(d * 129 + k) * 128 + n]);
        ushort u; __builtin_memcpy(&u, &v, 2);
        W1T[idx] = u;
    } else {
        const int j = idx - 65536;
        const int d = j >> 14;
        const int n = (j >> 7) & 127;
        const int kslot = j & 127;
        const int c = 32 * (kslot >> 5) + 16 * ((kslot >> 2) & 1)
                    + 4 * ((kslot >> 3) & 3) + (kslot & 3);
        __hip_bfloat16 v = __float2bfloat16(W2[(d * 128 + c) * 128 + n]);
        ushort u; __builtin_memcpy(&u, &v, 2);
        W2T[j] = u;
    }
}

// stage one 16KB half-tile (16 chunks of 1KB); wave wv stages chunks 2wv, 2wv+1.
// chunk c = tt*4+ks holds A-frags for t = 4*half+tt, kstep ks.
__device__ __forceinline__ void stage_half(const ushort* __restrict__ Wtile,
                                           int half, ushort* slot, int wv, int lane) {
    const int e4 = lane & 15;
    const int g  = lane >> 4;
    #pragma unroll
    for (int i = 0; i < 2; ++i) {
        const int c  = 2 * wv + i;
        const int tt = c >> 2;
        const int ks = c & 3;
        const ushort* gp = Wtile + (16 * (4 * half + tt) + e4) * 128 + g * 8 + 32 * ks;
        gl2lds16(gp, slot + c * 512);
    }
}

// ---- main fused kernel ----
// 8 waves x 16 edges = 128 edges/block. Transposed math: h^T = W1^T x^T.
// 16x16x32 MFMA. A (weights): row = lane&15 (ch%16), kslot = (lane>>4)*8+j+32ks.
// B (x / h): col = lane&15 (edge), same kslot layout.
// C: col = lane&15 (edge), ch = 16t + 4*(lane>>4) + reg.
__global__ __launch_bounds__(512, 6)
void rcpe_pipe3(const float* __restrict__ source,
                const float* __restrict__ target,
                const int*   __restrict__ edge,
                const float* __restrict__ freqs,
                const float* __restrict__ W1,      // f32, for k=128 rank-1 row
                const ushort* __restrict__ W1T,
                const float* __restrict__ b1,
                const float* __restrict__ gamma,
                const float* __restrict__ beta,
                const ushort* __restrict__ W2T,
                const float* __restrict__ b2,
                float* __restrict__ out,
                int E)
{
    __shared__ __align__(16) ushort wbuf[3][8192];    // 3 x 16 KB rotating slots
    __shared__ __align__(16) float feat_lds[4][128];
    __shared__ __align__(16) float freq_lds[4][64];

    const int tid  = threadIdx.x;     // 0..511
    const int wv   = tid >> 6;        // 0..7
    const int lane = tid & 63;
    const int e4   = lane & 15;
    const int g    = lane >> 4;       // 0..3
    const int ebase = blockIdx.x * 128;
    const int eg    = ebase + wv * 16 + e4;

    // ---- prologue: issue stages for phases 0 and 1 FIRST (FIFO-oldest) ----
    stage_half(W1T, 0, wbuf[0], wv, lane);   // phase 0: W1[0] t0-3
    stage_half(W1T, 1, wbuf[1], wv, lane);   // phase 1: W1[0] t4-7
    __builtin_amdgcn_sched_barrier(0);       // pin stage issue before other vmem

    if (tid < 256) ((float*)freq_lds)[tid] = freqs[tid];

    if (tid < 128) {
        const int e  = ebase + tid;
        const int ec = (e < E) ? e : (E - 1);
        const int s_i = edge[ec];
        const int t_i = edge[E + ec];
        const float sx = source[s_i * 3 + 0];
        const float sy = source[s_i * 3 + 1];
        const float sh = source[s_i * 3 + 2];
        const float tx = target[t_i * 5 + 0];
        const float ty = target[t_i * 5 + 1];
        const float th = target[t_i * 5 + 2];
        const float ts = target[t_i * 5 + 3];
        const float dx = sx - tx;
        const float dy = sy - ty;
        float a = sh - th + PI_F;
        a = fmodf(a, TWO_PI_F);
        if (a < 0.0f) a += TWO_PI_F;
        const float dh  = a - PI_F;
        const float ang = atan2f(dy, dx);
        const float tvx = ts * cosf(th);
        const float tvy = ts * sinf(th);
        const float closing = tvx * cosf(ang) + tvy * sinf(ang);
        feat_lds[0][tid] = dx;
        feat_lds[1][tid] = dy;
        feat_lds[2][tid] = dh;
        feat_lds[3][tid] = closing;
    }

    // y init: sum_d b2 (C layout: ch = 16t + 4g + r)
    float4v y[8];
    #pragma unroll
    for (int t = 0; t < 8; ++t) {
        float4v a = {0.f, 0.f, 0.f, 0.f};
        #pragma unroll
        for (int d = 0; d < 4; ++d) {
            const float4v bv = *(const float4v*)(b2 + d * 128 + 16 * t + 4 * g);
            #pragma unroll
            for (int r = 0; r < 4; ++r) a[r] += bv[r];
        }
        y[t] = a;
    }

    phase_barrier();   // phase-0 slot ready (leaves phase-1 stage in flight)

    #pragma unroll
    for (int d = 0; d < 4; ++d) {
        const int s0 = (4 * d)     % 3;
        const int s1 = (4 * d + 1) % 3;
        const int s2 = (4 * d + 2) % 3;
        const int s3 = (4 * d + 3) % 3;
        const int s4 = (4 * d + 4) % 3;   // == s1
        const int s5 = (4 * d + 5) % 3;   // == s2

        const float fe = feat_lds[d][wv * 16 + e4];

        // ===== phase 0: stage W2[d]h0 -> s2 ; trig ; GEMM1 t0-3 from s0 =====
        stage_half(W2T + d * 16384, 0, wbuf[s2], wv, lane);

        Frag xf[4];   // ks0=cos lo, ks1=cos hi, ks2=sin lo, ks3=sin hi
        {
            float cl[8], sl[8], ch8[8], sh8[8];
            #pragma unroll
            for (int j = 0; j < 8; ++j) {
                const float frL = freq_lds[d][8 * g + j];
                const float frH = freq_lds[d][32 + 8 * g + j];
                const float tL = __builtin_amdgcn_fractf(fe * frL);
                const float tH = __builtin_amdgcn_fractf(fe * frH);
                sl[j]  = __builtin_amdgcn_sinf(tL);
                cl[j]  = __builtin_amdgcn_cosf(tL);
                sh8[j] = __builtin_amdgcn_sinf(tH);
                ch8[j] = __builtin_amdgcn_cosf(tH);
            }
            #pragma unroll
            for (int p = 0; p < 4; ++p) {
                xf[0].u[p] = pack2(cl[2 * p],  cl[2 * p + 1]);
                xf[1].u[p] = pack2(ch8[2 * p], ch8[2 * p + 1]);
                xf[2].u[p] = pack2(sl[2 * p],  sl[2 * p + 1]);
                xf[3].u[p] = pack2(sh8[2 * p], sh8[2 * p + 1]);
            }
        }

        float4v hacc[8];
        __builtin_amdgcn_s_setprio(1);
        #pragma unroll
        for (int t = 0; t < 4; ++t) {
            const float4v bv = *(const float4v*)(b1 + d * 128 + 16 * t + 4 * g);
            float4v acc = {bv[0], bv[1], bv[2], bv[3]};
            #pragma unroll
            for (int ks = 0; ks < 4; ++ks) {
                const short8 aw = *(const short8*)&wbuf[s0][(t * 4 + ks) * 512 + lane * 8];
                acc = __builtin_amdgcn_mfma_f32_16x16x32_bf16(aw, xf[ks].s, acc, 0, 0, 0);
            }
            hacc[t] = acc;
        }
        __builtin_amdgcn_s_setprio(0);
        phase_barrier();

        // ===== phase 1: stage W2[d]h1 -> s3 ; GEMM1 t4-7 from s1 ; rank-1 =====
        stage_half(W2T + d * 16384, 1, wbuf[s3], wv, lane);

        __builtin_amdgcn_s_setprio(1);
        #pragma unroll
        for (int t = 4; t < 8; ++t) {
            const float4v bv = *(const float4v*)(b1 + d * 128 + 16 * t + 4 * g);
            float4v acc = {bv[0], bv[1], bv[2], bv[3]};
            #pragma unroll
            for (int ks = 0; ks < 4; ++ks) {
                const short8 aw = *(const short8*)&wbuf[s1][((t - 4) * 4 + ks) * 512 + lane * 8];
                acc = __builtin_amdgcn_mfma_f32_16x16x32_bf16(aw, xf[ks].s, acc, 0, 0, 0);
            }
            hacc[t] = acc;
        }
        __builtin_amdgcn_s_setprio(0);

        // rank-1: k=128 raw-feature column, exact f32
        #pragma unroll
        for (int t = 0; t < 8; ++t) {
            const float4v wv4 = *(const float4v*)(W1 + (d * 129 + 128) * 128 + 16 * t + 4 * g);
            #pragma unroll
            for (int r = 0; r < 4; ++r)
                hacc[t][r] = fmaf(fe, wv4[r], hacc[t][r]);
        }
        phase_barrier();

        // ===== phase 2: stage W1[d+1]h0 -> s4 ; LN ; pack ; GEMM2 t0-3 from s2 =====
        if (d < 3) stage_half(W1T + (d + 1) * 16384, 0, wbuf[s4], wv, lane);

        float sm = 0.f, sq = 0.f;
        #pragma unroll
        for (int t = 0; t < 8; ++t) {
            #pragma unroll
            for (int r = 0; r < 4; ++r) {
                const float v = hacc[t][r];
                sm += v;
                sq = fmaf(v, v, sq);
            }
        }
        sm += __shfl_xor(sm, 16, 64);
        sq += __shfl_xor(sq, 16, 64);
        sm += __shfl_xor(sm, 32, 64);
        sq += __shfl_xor(sq, 32, 64);
        const float mu   = sm * (1.f / 128.f);
        const float var  = sq * (1.f / 128.f) - mu * mu;
        const float rinv = rsqrtf(var + 1e-5f);
        #pragma unroll
        for (int t = 0; t < 8; ++t) {
            const float4v gv = *(const float4v*)(gamma + d * 128 + 16 * t + 4 * g);
            const float4v bv = *(const float4v*)(beta  + d * 128 + 16 * t + 4 * g);
            #pragma unroll
            for (int r = 0; r < 4; ++r) {
                float v = (hacc[t][r] - mu) * rinv;
                v = fmaf(v, gv[r], bv[r]);
                hacc[t][r] = fmaxf(v, 0.f);
            }
        }

        // zero-shuffle B-frags (pi-permuted W2T makes them lane-local)
        Frag bfr[4];
        #pragma unroll
        for (int ks = 0; ks < 4; ++ks) {
            bfr[ks].u[0] = pack2(hacc[2 * ks][0],     hacc[2 * ks][1]);
            bfr[ks].u[1] = pack2(hacc[2 * ks][2],     hacc[2 * ks][3]);
            bfr[ks].u[2] = pack2(hacc[2 * ks + 1][0], hacc[2 * ks + 1][1]);
            bfr[ks].u[3] = pack2(hacc[2 * ks + 1][2], hacc[2 * ks + 1][3]);
        }

        __builtin_amdgcn_s_setprio(1);
        #pragma unroll
        for (int t = 0; t < 4; ++t) {
            float4v acc = y[t];
            #pragma unroll
            for (int ks = 0; ks < 4; ++ks) {
                const short8 aw = *(const short8*)&wbuf[s2][(t * 4 + ks) * 512 + lane * 8];
                acc = __builtin_amdgcn_mfma_f32_16x16x32_bf16(aw, bfr[ks].s, acc, 0, 0, 0);
            }
            y[t] = acc;
        }
        __builtin_amdgcn_s_setprio(0);
        phase_barrier();

        // ===== phase 3: stage W1[d+1]h1 -> s5 ; GEMM2 t4-7 from s3 =====
        if (d < 3) stage_half(W1T + (d + 1) * 16384, 1, wbuf[s5], wv, lane);

        __builtin_amdgcn_s_setprio(1);
        #pragma unroll
        for (int t = 4; t < 8; ++t) {
            float4v acc = y[t];
            #pragma unroll
            for (int ks = 0; ks < 4; ++ks) {
                const short8 aw = *(const short8*)&wbuf[s3][((t - 4) * 4 + ks) * 512 + lane * 8];
                acc = __builtin_amdgcn_mfma_f32_16x16x32_bf16(aw, bfr[ks].s, acc, 0, 0, 0);
            }
            y[t] = acc;
        }
        __builtin_amdgcn_s_setprio(0);
        if (d < 3) phase_barrier();
    }

    // ---- store: 4 g-lanes per edge form full 64B sectors ----
    if (eg < E) {
        #pragma unroll
        for (int t = 0; t < 8; ++t) {
            *(float4v*)(out + eg * 128 + 16 * t + 4 * g) = y[t];
        }
    }
}

} // namespace

extern "C" void kernel_launch(void* const* d_in, const int* in_sizes, int n_in,
                              void* d_out, int out_size, void* d_ws, size_t ws_size,
                              hipStream_t stream) {
    const float* source = (const float*)d_in[0];
    const float* target = (const float*)d_in[1];
    const int*   edge   = (const int*)  d_in[2];
    const float* freqs  = (const float*)d_in[3];
    const float* W1     = (const float*)d_in[4];
    const float* b1     = (const float*)d_in[5];
    const float* gammap = (const float*)d_in[6];
    const float* betap  = (const float*)d_in[7];
    const float* W2     = (const float*)d_in[8];
    const float* b2     = (const float*)d_in[9];
    float* out = (float*)d_out;

    ushort* W1T = (ushort*)d_ws;                       // 131072 B
    ushort* W2T = (ushort*)((char*)d_ws + 131072);     // 131072 B

    const int E = in_sizes[2] / 2;      // edge is (2, E); E = 200000

    prep_weights<<<dim3(512), dim3(256), 0, stream>>>(W1, W2, W1T, W2T);

    const int nblocks = (E + 127) / 128;   // 1563 (tail block: 32 edges)
    rcpe_pipe3<<<dim3(nblocks), dim3(512), 0, stream>>>(
        source, target, edge, freqs, W1, W1T, b1, gammap, betap, W2T, b2, out, E);
}

// Round 7
// 525.931 us; speedup vs baseline: 1.6317x; 1.6317x over previous
//
#include <hip/hip_runtime.h>
#include <hip/hip_bf16.h>
#include <math.h>

namespace {

typedef __attribute__((ext_vector_type(8))) short  short8;
typedef __attribute__((ext_vector_type(4))) float  float4v;

constexpr float PI_F     = 3.14159265358979323846f;
constexpr float TWO_PI_F = 6.28318530717958647692f;

__device__ __forceinline__ unsigned pack2(float a, float b) {
    __hip_bfloat162 h = __float22bfloat162_rn(float2{a, b});
    unsigned r;
    __builtin_memcpy(&r, &h, 4);
    return r;
}

union Frag { unsigned u[4]; short8 s; };

__device__ __forceinline__ void gl2lds16(const void* g, void* l) {
    __builtin_amdgcn_global_load_lds(
        (const __attribute__((address_space(1))) void*)g,
        (__attribute__((address_space(3))) void*)l, 16, 0, 0);
}

// counted-vmcnt phase barrier: the ONLY vmem in the d-loop is the current
// phase's 2 stage-loads, so vmcnt(2) forces the previous phase's stage landed
// while leaving this phase's in flight. lgkmcnt(0) so no wave crosses with
// LDS reads of a soon-to-be-overwritten slot outstanding.
__device__ __forceinline__ void phase_barrier() {
    asm volatile("s_waitcnt vmcnt(2) lgkmcnt(0)" ::: "memory");
    __builtin_amdgcn_s_barrier();
    __builtin_amdgcn_sched_barrier(0);
}

// ---- prep: transpose + bf16 weights.
// W1T[d][n][k]   = W1[d][k][n]               (k < 128; k=128 handled as f32 rank-1)
// W2T[d][n][ks_] = W2[d][pi(ks_)][n], pi makes GEMM2's B-frag lane-local:
//   pi(kslot) = 32*(kslot>>5) + 16*((kslot>>2)&1) + 4*((kslot>>3)&3) + (kslot&3)
__global__ __launch_bounds__(256)
void prep_weights(const float* __restrict__ W1,
                  const float* __restrict__ W2,
                  ushort* __restrict__ W1T,
                  ushort* __restrict__ W2T) {
    const int idx = blockIdx.x * 256 + threadIdx.x;   // 0 .. 131071
    if (idx < 65536) {
        const int d = idx >> 14;
        const int n = (idx >> 7) & 127;
        const int k = idx & 127;
        __hip_bfloat16 v = __float2bfloat16(W1[(d * 129 + k) * 128 + n]);
        ushort u; __builtin_memcpy(&u, &v, 2);
        W1T[idx] = u;
    } else {
        const int j = idx - 65536;
        const int d = j >> 14;
        const int n = (j >> 7) & 127;
        const int kslot = j & 127;
        const int c = 32 * (kslot >> 5) + 16 * ((kslot >> 2) & 1)
                    + 4 * ((kslot >> 3) & 3) + (kslot & 3);
        __hip_bfloat16 v = __float2bfloat16(W2[(d * 128 + c) * 128 + n]);
        ushort u; __builtin_memcpy(&u, &v, 2);
        W2T[j] = u;
    }
}

// stage one 16KB half-tile (16 chunks of 1KB); wave wv stages chunks 2wv, 2wv+1.
// chunk c = tt*4+ks holds A-frags for t = 4*half+tt, kstep ks.
__device__ __forceinline__ void stage_half(const ushort* __restrict__ Wtile,
                                           int half, ushort* slot, int wv, int lane) {
    const int e4 = lane & 15;
    const int g  = lane >> 4;
    #pragma unroll
    for (int i = 0; i < 2; ++i) {
        const int c  = 2 * wv + i;
        const int tt = c >> 2;
        const int ks = c & 3;
        const ushort* gp = Wtile + (16 * (4 * half + tt) + e4) * 128 + g * 8 + 32 * ks;
        gl2lds16(gp, slot + c * 512);
    }
}

// ---- main fused kernel ----
// 8 waves x 16 edges = 128 edges/block. Transposed math: h^T = W1^T x^T.
// 16x16x32 MFMA. A (weights): row = lane&15 (ch%16), kslot = (lane>>4)*8+j+32ks.
// B (x / h): col = lane&15 (edge), same kslot layout.
// C: col = lane&15 (edge), ch = 16t + 4*(lane>>4) + reg.
__global__ __launch_bounds__(512, 4)
void rcpe_pipe3(const float* __restrict__ source,
                const float* __restrict__ target,
                const int*   __restrict__ edge,
                const float* __restrict__ freqs,
                const float* __restrict__ W1,      // f32, for k=128 rank-1 row
                const ushort* __restrict__ W1T,
                const float* __restrict__ b1,
                const float* __restrict__ gamma,
                const float* __restrict__ beta,
                const ushort* __restrict__ W2T,
                const float* __restrict__ b2,
                float* __restrict__ out,
                int E)
{
    __shared__ __align__(16) ushort wbuf[3][8192];    // 3 x 16 KB rotating slots
    __shared__ __align__(16) float b1_lds[4][128];
    __shared__ __align__(16) float gm_lds[4][128];
    __shared__ __align__(16) float bt_lds[4][128];
    __shared__ __align__(16) float w1r_lds[4][128];
    __shared__ __align__(16) float feat_lds[4][128];
    __shared__ __align__(16) float freq_lds[4][64];

    const int tid  = threadIdx.x;     // 0..511
    const int wv   = tid >> 6;        // 0..7
    const int lane = tid & 63;
    const int e4   = lane & 15;
    const int g    = lane >> 4;       // 0..3
    const int ebase = blockIdx.x * 128;
    const int eg    = ebase + wv * 16 + e4;

    // ---- prologue: issue stages for phases 0 and 1 FIRST (FIFO-oldest) ----
    stage_half(W1T, 0, wbuf[0], wv, lane);   // phase 0: W1[0] t0-3
    stage_half(W1T, 1, wbuf[1], wv, lane);   // phase 1: W1[0] t4-7
    __builtin_amdgcn_sched_barrier(0);       // pin stage issue before other vmem

    {   // param tables: 512 elements each, one per thread (prologue-only vmem)
        const int dd = tid >> 7, c = tid & 127;
        b1_lds[dd][c]  = b1[tid];
        gm_lds[dd][c]  = gamma[tid];
        bt_lds[dd][c]  = beta[tid];
        w1r_lds[dd][c] = W1[(dd * 129 + 128) * 128 + c];
    }
    if (tid < 256) ((float*)freq_lds)[tid] = freqs[tid];

    if (tid < 128) {
        const int e  = ebase + tid;
        const int ec = (e < E) ? e : (E - 1);
        const int s_i = edge[ec];
        const int t_i = edge[E + ec];
        const float sx = source[s_i * 3 + 0];
        const float sy = source[s_i * 3 + 1];
        const float sh = source[s_i * 3 + 2];
        const float tx = target[t_i * 5 + 0];
        const float ty = target[t_i * 5 + 1];
        const float th = target[t_i * 5 + 2];
        const float ts = target[t_i * 5 + 3];
        const float dx = sx - tx;
        const float dy = sy - ty;
        float a = sh - th + PI_F;
        a = fmodf(a, TWO_PI_F);
        if (a < 0.0f) a += TWO_PI_F;
        const float dh  = a - PI_F;
        const float ang = atan2f(dy, dx);
        const float tvx = ts * cosf(th);
        const float tvy = ts * sinf(th);
        const float closing = tvx * cosf(ang) + tvy * sinf(ang);
        feat_lds[0][tid] = dx;
        feat_lds[1][tid] = dy;
        feat_lds[2][tid] = dh;
        feat_lds[3][tid] = closing;
    }

    // y init: sum_d b2 (C layout: ch = 16t + 4g + r) — prologue-only global loads
    float4v y[8];
    #pragma unroll
    for (int t = 0; t < 8; ++t) {
        float4v a = {0.f, 0.f, 0.f, 0.f};
        #pragma unroll
        for (int d = 0; d < 4; ++d) {
            const float4v bv = *(const float4v*)(b2 + d * 128 + 16 * t + 4 * g);
            #pragma unroll
            for (int r = 0; r < 4; ++r) a[r] += bv[r];
        }
        y[t] = a;
    }

    phase_barrier();   // phase-0 slot ready

    #pragma unroll
    for (int d = 0; d < 4; ++d) {
        const int s0 = (4 * d)     % 3;
        const int s1 = (4 * d + 1) % 3;
        const int s2 = (4 * d + 2) % 3;
        const int s3 = (4 * d + 3) % 3;
        const int s4 = (4 * d + 4) % 3;   // == s1
        const int s5 = (4 * d + 5) % 3;   // == s2

        const float fe = feat_lds[d][wv * 16 + e4];

        // ===== phase 0: stage W2[d]h0 -> s2 ; trig ; GEMM1 t0-3 from s0 =====
        stage_half(W2T + d * 16384, 0, wbuf[s2], wv, lane);

        Frag xf[4];   // ks0=cos lo, ks1=cos hi, ks2=sin lo, ks3=sin hi
        {
            float cl[8], sl[8], ch8[8], sh8[8];
            #pragma unroll
            for (int j = 0; j < 8; ++j) {
                const float frL = freq_lds[d][8 * g + j];
                const float frH = freq_lds[d][32 + 8 * g + j];
                const float tL = __builtin_amdgcn_fractf(fe * frL);
                const float tH = __builtin_amdgcn_fractf(fe * frH);
                sl[j]  = __builtin_amdgcn_sinf(tL);
                cl[j]  = __builtin_amdgcn_cosf(tL);
                sh8[j] = __builtin_amdgcn_sinf(tH);
                ch8[j] = __builtin_amdgcn_cosf(tH);
            }
            #pragma unroll
            for (int p = 0; p < 4; ++p) {
                xf[0].u[p] = pack2(cl[2 * p],  cl[2 * p + 1]);
                xf[1].u[p] = pack2(ch8[2 * p], ch8[2 * p + 1]);
                xf[2].u[p] = pack2(sl[2 * p],  sl[2 * p + 1]);
                xf[3].u[p] = pack2(sh8[2 * p], sh8[2 * p + 1]);
            }
        }

        float4v hacc[8];
        __builtin_amdgcn_s_setprio(1);
        #pragma unroll
        for (int t = 0; t < 4; ++t) {
            float4v acc = *(const float4v*)&b1_lds[d][16 * t + 4 * g];
            #pragma unroll
            for (int ks = 0; ks < 4; ++ks) {
                const short8 aw = *(const short8*)&wbuf[s0][(t * 4 + ks) * 512 + lane * 8];
                acc = __builtin_amdgcn_mfma_f32_16x16x32_bf16(aw, xf[ks].s, acc, 0, 0, 0);
            }
            hacc[t] = acc;
        }
        __builtin_amdgcn_s_setprio(0);
        phase_barrier();

        // ===== phase 1: stage W2[d]h1 -> s3 ; GEMM1 t4-7 from s1 ; rank-1 =====
        stage_half(W2T + d * 16384, 1, wbuf[s3], wv, lane);

        __builtin_amdgcn_s_setprio(1);
        #pragma unroll
        for (int t = 4; t < 8; ++t) {
            float4v acc = *(const float4v*)&b1_lds[d][16 * t + 4 * g];
            #pragma unroll
            for (int ks = 0; ks < 4; ++ks) {
                const short8 aw = *(const short8*)&wbuf[s1][((t - 4) * 4 + ks) * 512 + lane * 8];
                acc = __builtin_amdgcn_mfma_f32_16x16x32_bf16(aw, xf[ks].s, acc, 0, 0, 0);
            }
            hacc[t] = acc;
        }
        __builtin_amdgcn_s_setprio(0);

        // rank-1: k=128 raw-feature column, exact f32 (from LDS table)
        #pragma unroll
        for (int t = 0; t < 8; ++t) {
            const float4v wv4 = *(const float4v*)&w1r_lds[d][16 * t + 4 * g];
            #pragma unroll
            for (int r = 0; r < 4; ++r)
                hacc[t][r] = fmaf(fe, wv4[r], hacc[t][r]);
        }
        phase_barrier();

        // ===== phase 2: stage W1[d+1]h0 -> s4 ; LN ; pack ; GEMM2 t0-3 from s2 =====
        if (d < 3) stage_half(W1T + (d + 1) * 16384, 0, wbuf[s4], wv, lane);

        float sm = 0.f, sq = 0.f;
        #pragma unroll
        for (int t = 0; t < 8; ++t) {
            #pragma unroll
            for (int r = 0; r < 4; ++r) {
                const float v = hacc[t][r];
                sm += v;
                sq = fmaf(v, v, sq);
            }
        }
        sm += __shfl_xor(sm, 16, 64);
        sq += __shfl_xor(sq, 16, 64);
        sm += __shfl_xor(sm, 32, 64);
        sq += __shfl_xor(sq, 32, 64);
        const float mu   = sm * (1.f / 128.f);
        const float var  = sq * (1.f / 128.f) - mu * mu;
        const float rinv = rsqrtf(var + 1e-5f);
        #pragma unroll
        for (int t = 0; t < 8; ++t) {
            const float4v gv = *(const float4v*)&gm_lds[d][16 * t + 4 * g];
            const float4v bv = *(const float4v*)&bt_lds[d][16 * t + 4 * g];
            #pragma unroll
            for (int r = 0; r < 4; ++r) {
                float v = (hacc[t][r] - mu) * rinv;
                v = fmaf(v, gv[r], bv[r]);
                hacc[t][r] = fmaxf(v, 0.f);
            }
        }

        // zero-shuffle B-frags (pi-permuted W2T makes them lane-local)
        Frag bfr[4];
        #pragma unroll
        for (int ks = 0; ks < 4; ++ks) {
            bfr[ks].u[0] = pack2(hacc[2 * ks][0],     hacc[2 * ks][1]);
            bfr[ks].u[1] = pack2(hacc[2 * ks][2],     hacc[2 * ks][3]);
            bfr[ks].u[2] = pack2(hacc[2 * ks + 1][0], hacc[2 * ks + 1][1]);
            bfr[ks].u[3] = pack2(hacc[2 * ks + 1][2], hacc[2 * ks + 1][3]);
        }

        __builtin_amdgcn_s_setprio(1);
        #pragma unroll
        for (int t = 0; t < 4; ++t) {
            float4v acc = y[t];
            #pragma unroll
            for (int ks = 0; ks < 4; ++ks) {
                const short8 aw = *(const short8*)&wbuf[s2][(t * 4 + ks) * 512 + lane * 8];
                acc = __builtin_amdgcn_mfma_f32_16x16x32_bf16(aw, bfr[ks].s, acc, 0, 0, 0);
            }
            y[t] = acc;
        }
        __builtin_amdgcn_s_setprio(0);
        phase_barrier();

        // ===== phase 3: stage W1[d+1]h1 -> s5 ; GEMM2 t4-7 from s3 =====
        if (d < 3) stage_half(W1T + (d + 1) * 16384, 1, wbuf[s5], wv, lane);

        __builtin_amdgcn_s_setprio(1);
        #pragma unroll
        for (int t = 4; t < 8; ++t) {
            float4v acc = y[t];
            #pragma unroll
            for (int ks = 0; ks < 4; ++ks) {
                const short8 aw = *(const short8*)&wbuf[s3][((t - 4) * 4 + ks) * 512 + lane * 8];
                acc = __builtin_amdgcn_mfma_f32_16x16x32_bf16(aw, bfr[ks].s, acc, 0, 0, 0);
            }
            y[t] = acc;
        }
        __builtin_amdgcn_s_setprio(0);
        if (d < 3) phase_barrier();
    }

    // ---- store: 4 g-lanes per edge form full 64B sectors ----
    if (eg < E) {
        #pragma unroll
        for (int t = 0; t < 8; ++t) {
            *(float4v*)(out + eg * 128 + 16 * t + 4 * g) = y[t];
        }
    }
}

} // namespace

extern "C" void kernel_launch(void* const* d_in, const int* in_sizes, int n_in,
                              void* d_out, int out_size, void* d_ws, size_t ws_size,
                              hipStream_t stream) {
    const float* source = (const float*)d_in[0];
    const float* target = (const float*)d_in[1];
    const int*   edge   = (const int*)  d_in[2];
    const float* freqs  = (const float*)d_in[3];
    const float* W1     = (const float*)d_in[4];
    const float* b1     = (const float*)d_in[5];
    const float* gammap = (const float*)d_in[6];
    const float* betap  = (const float*)d_in[7];
    const float* W2     = (const float*)d_in[8];
    const float* b2     = (const float*)d_in[9];
    float* out = (float*)d_out;

    ushort* W1T = (ushort*)d_ws;                       // 131072 B
    ushort* W2T = (ushort*)((char*)d_ws + 131072);     // 131072 B

    const int E = in_sizes[2] / 2;      // edge is (2, E); E = 200000

    prep_weights<<<dim3(512), dim3(256), 0, stream>>>(W1, W2, W1T, W2T);

    const int nblocks = (E + 127) / 128;   // 1563 (tail block: 64 edges)
    rcpe_pipe3<<<dim3(nblocks), dim3(512), 0, stream>>>(
        source, target, edge, freqs, W1, W1T, b1, gammap, betap, W2T, b2, out, E);
}

// Round 8
// 121.193 us; speedup vs baseline: 7.0811x; 4.3396x over previous
//
#include <hip/hip_runtime.h>
#include <hip/hip_bf16.h>
#include <math.h>

namespace {

typedef __attribute__((ext_vector_type(8))) short  short8;
typedef __attribute__((ext_vector_type(4))) float  float4v;

constexpr float PI_F     = 3.14159265358979323846f;
constexpr float TWO_PI_F = 6.28318530717958647692f;

__device__ __forceinline__ unsigned pack2(float a, float b) {
    __hip_bfloat162 h = __float22bfloat162_rn(float2{a, b});
    unsigned r;
    __builtin_memcpy(&r, &h, 4);
    return r;
}

union Frag { unsigned u[4]; short8 s; };

__device__ __forceinline__ void gl2lds16(const void* g, void* l) {
    __builtin_amdgcn_global_load_lds(
        (const __attribute__((address_space(1))) void*)g,
        (__attribute__((address_space(3))) void*)l, 16, 0, 0);
}

// ---- prep: transpose + bf16 weights.
// W1T[d][n][k]   = W1[d][k][n]               (k < 128; k=128 handled as f32 rank-1)
// W2T[d][n][ks_] = W2[d][pi(ks_)][n], pi makes GEMM2's B-frag lane-local:
//   pi(kslot) = 32*(kslot>>5) + 16*((kslot>>2)&1) + 4*((kslot>>3)&3) + (kslot&3)
__global__ __launch_bounds__(256)
void prep_weights(const float* __restrict__ W1,
                  const float* __restrict__ W2,
                  ushort* __restrict__ W1T,
                  ushort* __restrict__ W2T) {
    const int idx = blockIdx.x * 256 + threadIdx.x;   // 0 .. 131071
    if (idx < 65536) {
        const int d = idx >> 14;
        const int n = (idx >> 7) & 127;
        const int k = idx & 127;
        __hip_bfloat16 v = __float2bfloat16(W1[(d * 129 + k) * 128 + n]);
        ushort u; __builtin_memcpy(&u, &v, 2);
        W1T[idx] = u;
    } else {
        const int j = idx - 65536;
        const int d = j >> 14;
        const int n = (j >> 7) & 127;
        const int kslot = j & 127;
        const int c = 32 * (kslot >> 5) + 16 * ((kslot >> 2) & 1)
                    + 4 * ((kslot >> 3) & 3) + (kslot & 3);
        __hip_bfloat16 v = __float2bfloat16(W2[(d * 128 + c) * 128 + n]);
        ushort u; __builtin_memcpy(&u, &v, 2);
        W2T[j] = u;
    }
}

// stage one 32KB tile with 4 waves: wave wv stages t = 2wv, 2wv+1 (8 x 1KB chunks).
// chunk c = t*4+ks holds the A-frags for channel-tile t, kstep ks.
__device__ __forceinline__ void stage_tile4(const ushort* __restrict__ Wtile,
                                            ushort* dst, int wv, int lane) {
    const int e4 = lane & 15;
    const int g  = lane >> 4;
    #pragma unroll
    for (int i = 0; i < 8; ++i) {
        const int c  = 8 * wv + i;
        const int tt = c >> 2;
        const int ks = c & 3;
        const ushort* gp = Wtile + (16 * tt + e4) * 128 + g * 8 + 32 * ks;
        gl2lds16(gp, dst + c * 512);
    }
}

// ---- main fused kernel ----
// 4 waves x 32 edges (2 groups of 16) = 128 edges/block. h^T = W1^T x^T.
// 16x16x32 MFMA. A (weights): row = lane&15 (ch%16), kslot = (lane>>4)*8+j+32ks.
// B (x / h): col = lane&15 (edge), same kslot layout.  Each A-frag ds_read
// feeds BOTH edge-groups' MFMAs -> half the LDS weight traffic per edge.
// C: col = lane&15 (edge), ch = 16t + 4*(lane>>4) + reg.
__global__ __launch_bounds__(256, 2)
void rcpe_dual(const float* __restrict__ source,
               const float* __restrict__ target,
               const int*   __restrict__ edge,
               const float* __restrict__ freqs,
               const float* __restrict__ W1,      // f32, for k=128 rank-1 row
               const ushort* __restrict__ W1T,
               const float* __restrict__ b1,
               const float* __restrict__ gamma,
               const float* __restrict__ beta,
               const ushort* __restrict__ W2T,
               const float* __restrict__ b2,
               float* __restrict__ out,
               int E)
{
    __shared__ __align__(16) ushort wbuf[2][16384];   // ping-pong 2 x 32 KB
    __shared__ __align__(16) float b1_lds[4][128];
    __shared__ __align__(16) float gm_lds[4][128];
    __shared__ __align__(16) float bt_lds[4][128];
    __shared__ __align__(16) float w1r_lds[4][128];
    __shared__ __align__(16) float feat_lds[4][128];
    __shared__ __align__(16) float freq_lds[4][64];

    const int tid  = threadIdx.x;     // 0..255
    const int wv   = tid >> 6;        // 0..3
    const int lane = tid & 63;
    const int e4   = lane & 15;
    const int g    = lane >> 4;       // 0..3
    const int ebase = blockIdx.x * 128;
    const int eg0   = ebase + wv * 32 + e4;        // group A edge
    const int eg1   = eg0 + 16;                    // group B edge

    // ---- prologue: issue first stage, then fill tables ----
    stage_tile4(W1T, wbuf[0], wv, lane);   // W1[d=0] -> buf0

    #pragma unroll
    for (int i = 0; i < 2; ++i) {     // param tables: 512 elems each, 256 threads
        const int idx = tid + 256 * i;
        const int dd = idx >> 7, c = idx & 127;
        b1_lds[dd][c]  = b1[idx];
        gm_lds[dd][c]  = gamma[idx];
        bt_lds[dd][c]  = beta[idx];
        w1r_lds[dd][c] = W1[(dd * 129 + 128) * 128 + c];
    }
    ((float*)freq_lds)[tid] = freqs[tid];   // freqs is [4][64] = 256

    if (tid < 128) {
        const int e  = ebase + tid;
        const int ec = (e < E) ? e : (E - 1);
        const int s_i = edge[ec];
        const int t_i = edge[E + ec];
        const float sx = source[s_i * 3 + 0];
        const float sy = source[s_i * 3 + 1];
        const float sh = source[s_i * 3 + 2];
        const float tx = target[t_i * 5 + 0];
        const float ty = target[t_i * 5 + 1];
        const float th = target[t_i * 5 + 2];
        const float ts = target[t_i * 5 + 3];
        const float dx = sx - tx;
        const float dy = sy - ty;
        float a = sh - th + PI_F;
        a = fmodf(a, TWO_PI_F);
        if (a < 0.0f) a += TWO_PI_F;
        const float dh  = a - PI_F;
        const float ang = atan2f(dy, dx);
        const float tvx = ts * cosf(th);
        const float tvy = ts * sinf(th);
        const float closing = tvx * cosf(ang) + tvy * sinf(ang);
        feat_lds[0][tid] = dx;
        feat_lds[1][tid] = dy;
        feat_lds[2][tid] = dh;
        feat_lds[3][tid] = closing;
    }

    // y init: sum_d b2 (C layout: ch = 16t + 4g + r) — prologue-only global loads
    float4v yA[8], yB[8];
    #pragma unroll
    for (int t = 0; t < 8; ++t) {
        float4v a = {0.f, 0.f, 0.f, 0.f};
        #pragma unroll
        for (int d = 0; d < 4; ++d) {
            const float4v bv = *(const float4v*)(b2 + d * 128 + 16 * t + 4 * g);
            #pragma unroll
            for (int r = 0; r < 4; ++r) a[r] += bv[r];
        }
        yA[t] = a;
        yB[t] = a;
    }

    __syncthreads();   // buf0 staged; tables ready

    #pragma unroll 1
    for (int d = 0; d < 4; ++d) {
        // ===== phase A: stage W2[d]->buf1 ; trig ; dual GEMM1 from buf0 =====
        stage_tile4(W2T + d * 16384, wbuf[1], wv, lane);

        const float feA = feat_lds[d][wv * 32 + e4];
        const float feB = feat_lds[d][wv * 32 + 16 + e4];

        Frag xfA[4], xfB[4];   // ks0=cos lo, ks1=cos hi, ks2=sin lo, ks3=sin hi
        #pragma unroll
        for (int grp = 0; grp < 2; ++grp) {
            const float fe = grp ? feB : feA;
            Frag* xf = grp ? xfB : xfA;
            float cl[8], sl[8], ch8[8], sh8[8];
            #pragma unroll
            for (int j = 0; j < 8; ++j) {
                const float frL = freq_lds[d][8 * g + j];
                const float frH = freq_lds[d][32 + 8 * g + j];
                const float tL = __builtin_amdgcn_fractf(fe * frL);
                const float tH = __builtin_amdgcn_fractf(fe * frH);
                sl[j]  = __builtin_amdgcn_sinf(tL);
                cl[j]  = __builtin_amdgcn_cosf(tL);
                sh8[j] = __builtin_amdgcn_sinf(tH);
                ch8[j] = __builtin_amdgcn_cosf(tH);
            }
            #pragma unroll
            for (int p = 0; p < 4; ++p) {
                xf[0].u[p] = pack2(cl[2 * p],  cl[2 * p + 1]);
                xf[1].u[p] = pack2(ch8[2 * p], ch8[2 * p + 1]);
                xf[2].u[p] = pack2(sl[2 * p],  sl[2 * p + 1]);
                xf[3].u[p] = pack2(sh8[2 * p], sh8[2 * p + 1]);
            }
        }

        float4v haccA[8], haccB[8];
        #pragma unroll
        for (int t = 0; t < 8; ++t) {
            const float4v bv = *(const float4v*)&b1_lds[d][16 * t + 4 * g];
            float4v accA = {bv[0], bv[1], bv[2], bv[3]};
            float4v accB = accA;
            #pragma unroll
            for (int ks = 0; ks < 4; ++ks) {
                const short8 aw = *(const short8*)&wbuf[0][(t * 4 + ks) * 512 + lane * 8];
                accA = __builtin_amdgcn_mfma_f32_16x16x32_bf16(aw, xfA[ks].s, accA, 0, 0, 0);
                accB = __builtin_amdgcn_mfma_f32_16x16x32_bf16(aw, xfB[ks].s, accB, 0, 0, 0);
            }
            haccA[t] = accA;
            haccB[t] = accB;
        }

        // rank-1: k=128 raw-feature column, exact f32 (from LDS table)
        #pragma unroll
        for (int t = 0; t < 8; ++t) {
            const float4v wv4 = *(const float4v*)&w1r_lds[d][16 * t + 4 * g];
            #pragma unroll
            for (int r = 0; r < 4; ++r) {
                haccA[t][r] = fmaf(feA, wv4[r], haccA[t][r]);
                haccB[t][r] = fmaf(feB, wv4[r], haccB[t][r]);
            }
        }

        __syncthreads();   // buf1 (W2[d]) staged; buf0 free to overwrite

        // ===== phase B: stage W1[d+1]->buf0 ; LN ; pack ; dual GEMM2 from buf1 =====
        if (d < 3) stage_tile4(W1T + (d + 1) * 16384, wbuf[0], wv, lane);

        float smA = 0.f, sqA = 0.f, smB = 0.f, sqB = 0.f;
        #pragma unroll
        for (int t = 0; t < 8; ++t) {
            #pragma unroll
            for (int r = 0; r < 4; ++r) {
                const float vA = haccA[t][r];
                const float vB = haccB[t][r];
                smA += vA;  sqA = fmaf(vA, vA, sqA);
                smB += vB;  sqB = fmaf(vB, vB, sqB);
            }
        }
        smA += __shfl_xor(smA, 16, 64);
        sqA += __shfl_xor(sqA, 16, 64);
        smB += __shfl_xor(smB, 16, 64);
        sqB += __shfl_xor(sqB, 16, 64);
        smA += __shfl_xor(smA, 32, 64);
        sqA += __shfl_xor(sqA, 32, 64);
        smB += __shfl_xor(smB, 32, 64);
        sqB += __shfl_xor(sqB, 32, 64);
        const float muA   = smA * (1.f / 128.f);
        const float muB   = smB * (1.f / 128.f);
        const float rinvA = rsqrtf(sqA * (1.f / 128.f) - muA * muA + 1e-5f);
        const float rinvB = rsqrtf(sqB * (1.f / 128.f) - muB * muB + 1e-5f);
        #pragma unroll
        for (int t = 0; t < 8; ++t) {
            const float4v gv = *(const float4v*)&gm_lds[d][16 * t + 4 * g];
            const float4v bv = *(const float4v*)&bt_lds[d][16 * t + 4 * g];
            #pragma unroll
            for (int r = 0; r < 4; ++r) {
                float vA = (haccA[t][r] - muA) * rinvA;
                float vB = (haccB[t][r] - muB) * rinvB;
                vA = fmaf(vA, gv[r], bv[r]);
                vB = fmaf(vB, gv[r], bv[r]);
                haccA[t][r] = fmaxf(vA, 0.f);
                haccB[t][r] = fmaxf(vB, 0.f);
            }
        }

        // zero-shuffle B-frags (pi-permuted W2T makes them lane-local)
        Frag bfrA[4], bfrB[4];
        #pragma unroll
        for (int ks = 0; ks < 4; ++ks) {
            bfrA[ks].u[0] = pack2(haccA[2 * ks][0],     haccA[2 * ks][1]);
            bfrA[ks].u[1] = pack2(haccA[2 * ks][2],     haccA[2 * ks][3]);
            bfrA[ks].u[2] = pack2(haccA[2 * ks + 1][0], haccA[2 * ks + 1][1]);
            bfrA[ks].u[3] = pack2(haccA[2 * ks + 1][2], haccA[2 * ks + 1][3]);
            bfrB[ks].u[0] = pack2(haccB[2 * ks][0],     haccB[2 * ks][1]);
            bfrB[ks].u[1] = pack2(haccB[2 * ks][2],     haccB[2 * ks][3]);
            bfrB[ks].u[2] = pack2(haccB[2 * ks + 1][0], haccB[2 * ks + 1][1]);
            bfrB[ks].u[3] = pack2(haccB[2 * ks + 1][2], haccB[2 * ks + 1][3]);
        }

        #pragma unroll
        for (int t = 0; t < 8; ++t) {
            float4v accA = yA[t];
            float4v accB = yB[t];
            #pragma unroll
            for (int ks = 0; ks < 4; ++ks) {
                const short8 aw = *(const short8*)&wbuf[1][(t * 4 + ks) * 512 + lane * 8];
                accA = __builtin_amdgcn_mfma_f32_16x16x32_bf16(aw, bfrA[ks].s, accA, 0, 0, 0);
                accB = __builtin_amdgcn_mfma_f32_16x16x32_bf16(aw, bfrB[ks].s, accB, 0, 0, 0);
            }
            yA[t] = accA;
            yB[t] = accB;
        }

        __syncthreads();   // buf0 (W1[d+1]) staged; buf1 free for next d
    }

    // ---- store: 4 g-lanes per edge form full 64B sectors ----
    if (eg0 < E) {
        #pragma unroll
        for (int t = 0; t < 8; ++t)
            *(float4v*)(out + eg0 * 128 + 16 * t + 4 * g) = yA[t];
    }
    if (eg1 < E) {
        #pragma unroll
        for (int t = 0; t < 8; ++t)
            *(float4v*)(out + eg1 * 128 + 16 * t + 4 * g) = yB[t];
    }
}

} // namespace

extern "C" void kernel_launch(void* const* d_in, const int* in_sizes, int n_in,
                              void* d_out, int out_size, void* d_ws, size_t ws_size,
                              hipStream_t stream) {
    const float* source = (const float*)d_in[0];
    const float* target = (const float*)d_in[1];
    const int*   edge   = (const int*)  d_in[2];
    const float* freqs  = (const float*)d_in[3];
    const float* W1     = (const float*)d_in[4];
    const float* b1     = (const float*)d_in[5];
    const float* gammap = (const float*)d_in[6];
    const float* betap  = (const float*)d_in[7];
    const float* W2     = (const float*)d_in[8];
    const float* b2     = (const float*)d_in[9];
    float* out = (float*)d_out;

    ushort* W1T = (ushort*)d_ws;                       // 131072 B
    ushort* W2T = (ushort*)((char*)d_ws + 131072);     // 131072 B

    const int E = in_sizes[2] / 2;      // edge is (2, E); E = 200000

    prep_weights<<<dim3(512), dim3(256), 0, stream>>>(W1, W2, W1T, W2T);

    const int nblocks = (E + 127) / 128;   // 1563 (tail block: 64 edges)
    rcpe_dual<<<dim3(nblocks), dim3(256), 0, stream>>>(
        source, target, edge, freqs, W1, W1T, b1, gammap, betap, W2T, b2, out, E);
}

// Round 9
// 111.801 us; speedup vs baseline: 7.6760x; 1.0840x over previous
//
#include <hip/hip_runtime.h>
#include <hip/hip_bf16.h>
#include <math.h>

namespace {

typedef __attribute__((ext_vector_type(8))) short  short8;
typedef __attribute__((ext_vector_type(4))) float  float4v;

constexpr float PI_F     = 3.14159265358979323846f;
constexpr float TWO_PI_F = 6.28318530717958647692f;

__device__ __forceinline__ unsigned pack2(float a, float b) {
    __hip_bfloat162 h = __float22bfloat162_rn(float2{a, b});
    unsigned r;
    __builtin_memcpy(&r, &h, 4);
    return r;
}

union Frag { unsigned u[4]; short8 s; };

__device__ __forceinline__ void gl2lds16(const void* g, void* l) {
    __builtin_amdgcn_global_load_lds(
        (const __attribute__((address_space(1))) void*)g,
        (__attribute__((address_space(3))) void*)l, 16, 0, 0);
}

// counted phase barrier: vmcnt(2) leaves THIS phase's 2 stage-loads in flight,
// forces the previous phase's stage landed. lgkmcnt(0): our ds reads/writes
// retired before signaling. sched_barrier(0): nothing hoists above the waits.
__device__ __forceinline__ void pb2() {
    asm volatile("s_waitcnt vmcnt(2) lgkmcnt(0)" ::: "memory");
    __builtin_amdgcn_s_barrier();
    __builtin_amdgcn_sched_barrier(0);
}
__device__ __forceinline__ void pb0() {
    asm volatile("s_waitcnt vmcnt(0) lgkmcnt(0)" ::: "memory");
    __builtin_amdgcn_s_barrier();
    __builtin_amdgcn_sched_barrier(0);
}

// ---- prep: transpose + bf16 weights.
// W1T[d][n][k]   = W1[d][k][n]               (k < 128; k=128 handled as f32 rank-1)
// W2T[d][n][ks_] = W2[d][pi(ks_)][n], pi makes GEMM2's B-frag lane-local:
//   pi(kslot) = 32*(kslot>>5) + 16*((kslot>>2)&1) + 4*((kslot>>3)&3) + (kslot&3)
__global__ __launch_bounds__(256)
void prep_weights(const float* __restrict__ W1,
                  const float* __restrict__ W2,
                  ushort* __restrict__ W1T,
                  ushort* __restrict__ W2T) {
    const int idx = blockIdx.x * 256 + threadIdx.x;   // 0 .. 131071
    if (idx < 65536) {
        const int d = idx >> 14;
        const int n = (idx >> 7) & 127;
        const int k = idx & 127;
        __hip_bfloat16 v = __float2bfloat16(W1[(d * 129 + k) * 128 + n]);
        ushort u; __builtin_memcpy(&u, &v, 2);
        W1T[idx] = u;
    } else {
        const int j = idx - 65536;
        const int d = j >> 14;
        const int n = (j >> 7) & 127;
        const int kslot = j & 127;
        const int c = 32 * (kslot >> 5) + 16 * ((kslot >> 2) & 1)
                    + 4 * ((kslot >> 3) & 3) + (kslot & 3);
        __hip_bfloat16 v = __float2bfloat16(W2[(d * 128 + c) * 128 + n]);
        ushort u; __builtin_memcpy(&u, &v, 2);
        W2T[j] = u;
    }
}

// stage one 16KB half-tile (16 x 1KB chunks); wave wv stages chunks 2wv, 2wv+1.
// chunk c = tt*4+ks holds A-frags for channel-tile t = 4*half+tt, kstep ks.
__device__ __forceinline__ void stage_half(const ushort* __restrict__ Wtile,
                                           int half, ushort* slot, int wv, int lane) {
    const int e4 = lane & 15;
    const int g  = lane >> 4;
    #pragma unroll
    for (int i = 0; i < 2; ++i) {
        const int c  = 2 * wv + i;
        const int tt = c >> 2;
        const int ks = c & 3;
        const ushort* gp = Wtile + (16 * (4 * half + tt) + e4) * 128 + g * 8 + 32 * ks;
        gl2lds16(gp, slot + c * 512);
    }
}

// ---- main fused kernel ----
// 8 waves x 16 edges = 128 edges/block. Transposed math: h^T = W1^T x^T.
// 16x16x32 MFMA. A (weights): row = lane&15 (ch%16), kslot = (lane>>4)*8+j+32ks.
// B (x / h): col = lane&15 (edge), same kslot layout.
// C: col = lane&15 (edge), ch = 16t + 4*(lane>>4) + reg.
// 4 phases per d; 3 rotating 16KB slots; stage issued 2 phases ahead of use.
__global__ __launch_bounds__(512, 4)
void rcpe_rot(const float* __restrict__ source,
              const float* __restrict__ target,
              const int*   __restrict__ edge,
              const float* __restrict__ freqs,
              const float* __restrict__ W1,      // f32, for k=128 rank-1 row
              const ushort* __restrict__ W1T,
              const float* __restrict__ b1,
              const float* __restrict__ gamma,
              const float* __restrict__ beta,
              const ushort* __restrict__ W2T,
              const float* __restrict__ b2,
              float* __restrict__ out,
              int E)
{
    __shared__ __align__(16) ushort wbuf[3][8192];    // 3 x 16 KB rotating slots
    __shared__ __align__(16) float b1_lds[4][128];
    __shared__ __align__(16) float gm_lds[4][128];
    __shared__ __align__(16) float bt_lds[4][128];
    __shared__ __align__(16) float w1r_lds[4][128];
    __shared__ __align__(16) float feat_lds[4][128];
    __shared__ __align__(16) float freq_lds[4][64];

    const int tid  = threadIdx.x;     // 0..511
    const int wv   = tid >> 6;        // 0..7
    const int lane = tid & 63;
    const int e4   = lane & 15;
    const int g    = lane >> 4;       // 0..3
    const int ebase = blockIdx.x * 128;
    const int eg    = ebase + wv * 16 + e4;

    // ---- prologue: issue phase-0 and phase-1 stages FIRST (oldest in FIFO) ----
    stage_half(W1T, 0, wbuf[0], wv, lane);   // phase 0 data: W1[0] t0-3
    stage_half(W1T, 1, wbuf[1], wv, lane);   // phase 1 data: W1[0] t4-7
    __builtin_amdgcn_sched_barrier(0);       // pin stage issue before other vmem

    {   // param tables (prologue-only vmem; loop has ONLY stage loads as vmem)
        const int dd = tid >> 7, c = tid & 127;
        b1_lds[dd][c]  = b1[tid];
        gm_lds[dd][c]  = gamma[tid];
        bt_lds[dd][c]  = beta[tid];
        w1r_lds[dd][c] = W1[(dd * 129 + 128) * 128 + c];
    }
    if (tid < 256) ((float*)freq_lds)[tid] = freqs[tid];

    if (tid < 128) {
        const int e  = ebase + tid;
        const int ec = (e < E) ? e : (E - 1);
        const int s_i = edge[ec];
        const int t_i = edge[E + ec];
        const float sx = source[s_i * 3 + 0];
        const float sy = source[s_i * 3 + 1];
        const float sh = source[s_i * 3 + 2];
        const float tx = target[t_i * 5 + 0];
        const float ty = target[t_i * 5 + 1];
        const float th = target[t_i * 5 + 2];
        const float ts = target[t_i * 5 + 3];
        const float dx = sx - tx;
        const float dy = sy - ty;
        float a = sh - th + PI_F;
        a = fmodf(a, TWO_PI_F);
        if (a < 0.0f) a += TWO_PI_F;
        const float dh  = a - PI_F;
        const float ang = atan2f(dy, dx);
        const float tvx = ts * cosf(th);
        const float tvy = ts * sinf(th);
        const float closing = tvx * cosf(ang) + tvy * sinf(ang);
        feat_lds[0][tid] = dx;
        feat_lds[1][tid] = dy;
        feat_lds[2][tid] = dh;
        feat_lds[3][tid] = closing;
    }

    // y init: sum_d b2 (C layout: ch = 16t + 4g + r)
    float4v y[8];
    #pragma unroll
    for (int t = 0; t < 8; ++t) {
        float4v a = {0.f, 0.f, 0.f, 0.f};
        #pragma unroll
        for (int d = 0; d < 4; ++d) {
            const float4v bv = *(const float4v*)(b2 + d * 128 + 16 * t + 4 * g);
            #pragma unroll
            for (int r = 0; r < 4; ++r) a[r] += bv[r];
        }
        y[t] = a;
    }

    pb2();   // params drained by their own dependency waits; slots 0,1 landed

    // rotating slot pointers: su = this phase's data, s1a = next, s2a = stage dst
    ushort* su  = wbuf[0];
    ushort* s1a = wbuf[1];
    ushort* s2a = wbuf[2];
    #define ROTATE() { ushort* _t = su; su = s1a; s1a = s2a; s2a = _t; }

    #pragma unroll 1
    for (int d = 0; d < 4; ++d) {
        const float fe = feat_lds[d][wv * 16 + e4];

        // ===== P0: stage W2[d]h0 -> s2a ; trig ; GEMM1 t0-3 from su =====
        stage_half(W2T + d * 16384, 0, s2a, wv, lane);

        Frag xf[4];   // ks0=cos lo, ks1=cos hi, ks2=sin lo, ks3=sin hi
        {
            float cl[8], sl[8], ch8[8], sh8[8];
            #pragma unroll
            for (int j = 0; j < 8; ++j) {
                const float frL = freq_lds[d][8 * g + j];
                const float frH = freq_lds[d][32 + 8 * g + j];
                const float tL = __builtin_amdgcn_fractf(fe * frL);
                const float tH = __builtin_amdgcn_fractf(fe * frH);
                sl[j]  = __builtin_amdgcn_sinf(tL);
                cl[j]  = __builtin_amdgcn_cosf(tL);
                sh8[j] = __builtin_amdgcn_sinf(tH);
                ch8[j] = __builtin_amdgcn_cosf(tH);
            }
            #pragma unroll
            for (int p = 0; p < 4; ++p) {
                xf[0].u[p] = pack2(cl[2 * p],  cl[2 * p + 1]);
                xf[1].u[p] = pack2(ch8[2 * p], ch8[2 * p + 1]);
                xf[2].u[p] = pack2(sl[2 * p],  sl[2 * p + 1]);
                xf[3].u[p] = pack2(sh8[2 * p], sh8[2 * p + 1]);
            }
        }

        float4v hacc[8];
        __builtin_amdgcn_s_setprio(1);
        #pragma unroll
        for (int t = 0; t < 4; ++t) {
            float4v acc = *(const float4v*)&b1_lds[d][16 * t + 4 * g];
            #pragma unroll
            for (int ks = 0; ks < 4; ++ks) {
                const short8 aw = *(const short8*)&su[(t * 4 + ks) * 512 + lane * 8];
                acc = __builtin_amdgcn_mfma_f32_16x16x32_bf16(aw, xf[ks].s, acc, 0, 0, 0);
            }
            hacc[t] = acc;
        }
        __builtin_amdgcn_s_setprio(0);
        pb2();
        ROTATE();

        // ===== P1: stage W2[d]h1 -> s2a ; GEMM1 t4-7 from su ; rank-1 =====
        stage_half(W2T + d * 16384, 1, s2a, wv, lane);

        __builtin_amdgcn_s_setprio(1);
        #pragma unroll
        for (int t = 4; t < 8; ++t) {
            float4v acc = *(const float4v*)&b1_lds[d][16 * t + 4 * g];
            #pragma unroll
            for (int ks = 0; ks < 4; ++ks) {
                const short8 aw = *(const short8*)&su[((t - 4) * 4 + ks) * 512 + lane * 8];
                acc = __builtin_amdgcn_mfma_f32_16x16x32_bf16(aw, xf[ks].s, acc, 0, 0, 0);
            }
            hacc[t] = acc;
        }
        __builtin_amdgcn_s_setprio(0);

        #pragma unroll
        for (int t = 0; t < 8; ++t) {   // rank-1: k=128 raw-feature column, exact f32
            const float4v wv4 = *(const float4v*)&w1r_lds[d][16 * t + 4 * g];
            #pragma unroll
            for (int r = 0; r < 4; ++r)
                hacc[t][r] = fmaf(fe, wv4[r], hacc[t][r]);
        }
        pb2();
        ROTATE();

        // ===== P2: stage W1[d+1]h0 -> s2a ; LN ; pack ; GEMM2 t0-3 from su =====
        if (d < 3) stage_half(W1T + (d + 1) * 16384, 0, s2a, wv, lane);

        float sm = 0.f, sq = 0.f;
        #pragma unroll
        for (int t = 0; t < 8; ++t) {
            #pragma unroll
            for (int r = 0; r < 4; ++r) {
                const float v = hacc[t][r];
                sm += v;
                sq = fmaf(v, v, sq);
            }
        }
        sm += __shfl_xor(sm, 16, 64);
        sq += __shfl_xor(sq, 16, 64);
        sm += __shfl_xor(sm, 32, 64);
        sq += __shfl_xor(sq, 32, 64);
        const float mu   = sm * (1.f / 128.f);
        const float var  = sq * (1.f / 128.f) - mu * mu;
        const float rinv = rsqrtf(var + 1e-5f);
        #pragma unroll
        for (int t = 0; t < 8; ++t) {
            const float4v gv = *(const float4v*)&gm_lds[d][16 * t + 4 * g];
            const float4v bv = *(const float4v*)&bt_lds[d][16 * t + 4 * g];
            #pragma unroll
            for (int r = 0; r < 4; ++r) {
                float v = (hacc[t][r] - mu) * rinv;
                v = fmaf(v, gv[r], bv[r]);
                hacc[t][r] = fmaxf(v, 0.f);
            }
        }

        Frag bfr[4];   // zero-shuffle B-frags (pi-permuted W2T makes them lane-local)
        #pragma unroll
        for (int ks = 0; ks < 4; ++ks) {
            bfr[ks].u[0] = pack2(hacc[2 * ks][0],     hacc[2 * ks][1]);
            bfr[ks].u[1] = pack2(hacc[2 * ks][2],     hacc[2 * ks][3]);
            bfr[ks].u[2] = pack2(hacc[2 * ks + 1][0], hacc[2 * ks + 1][1]);
            bfr[ks].u[3] = pack2(hacc[2 * ks + 1][2], hacc[2 * ks + 1][3]);
        }

        __builtin_amdgcn_s_setprio(1);
        #pragma unroll
        for (int t = 0; t < 4; ++t) {
            float4v acc = y[t];
            #pragma unroll
            for (int ks = 0; ks < 4; ++ks) {
                const short8 aw = *(const short8*)&su[(t * 4 + ks) * 512 + lane * 8];
                acc = __builtin_amdgcn_mfma_f32_16x16x32_bf16(aw, bfr[ks].s, acc, 0, 0, 0);
            }
            y[t] = acc;
        }
        __builtin_amdgcn_s_setprio(0);
        if (d < 3) pb2(); else pb0();   // no stage issued when d==3 -> counts shift
        ROTATE();

        // ===== P3: stage W1[d+1]h1 -> s2a ; GEMM2 t4-7 from su =====
        if (d < 3) stage_half(W1T + (d + 1) * 16384, 1, s2a, wv, lane);

        __builtin_amdgcn_s_setprio(1);
        #pragma unroll
        for (int t = 4; t < 8; ++t) {
            float4v acc = y[t];
            #pragma unroll
            for (int ks = 0; ks < 4; ++ks) {
                const short8 aw = *(const short8*)&su[((t - 4) * 4 + ks) * 512 + lane * 8];
                acc = __builtin_amdgcn_mfma_f32_16x16x32_bf16(aw, bfr[ks].s, acc, 0, 0, 0);
            }
            y[t] = acc;
        }
        __builtin_amdgcn_s_setprio(0);
        if (d < 3) pb2();
        ROTATE();
    }
    #undef ROTATE

    // ---- store: 4 g-lanes per edge form full 64B sectors ----
    if (eg < E) {
        #pragma unroll
        for (int t = 0; t < 8; ++t) {
            *(float4v*)(out + eg * 128 + 16 * t + 4 * g) = y[t];
        }
    }
}

} // namespace

extern "C" void kernel_launch(void* const* d_in, const int* in_sizes, int n_in,
                              void* d_out, int out_size, void* d_ws, size_t ws_size,
                              hipStream_t stream) {
    const float* source = (const float*)d_in[0];
    const float* target = (const float*)d_in[1];
    const int*   edge   = (const int*)  d_in[2];
    const float* freqs  = (const float*)d_in[3];
    const float* W1     = (const float*)d_in[4];
    const float* b1     = (const float*)d_in[5];
    const float* gammap = (const float*)d_in[6];
    const float* betap  = (const float*)d_in[7];
    const float* W2     = (const float*)d_in[8];
    const float* b2     = (const float*)d_in[9];
    float* out = (float*)d_out;

    ushort* W1T = (ushort*)d_ws;                       // 131072 B
    ushort* W2T = (ushort*)((char*)d_ws + 131072);     // 131072 B

    const int E = in_sizes[2] / 2;      // edge is (2, E); E = 200000

    prep_weights<<<dim3(512), dim3(256), 0, stream>>>(W1, W2, W1T, W2T);

    const int nblocks = (E + 127) / 128;   // 1563 (tail block: 64 edges)
    rcpe_rot<<<dim3(nblocks), dim3(512), 0, stream>>>(
        source, target, edge, freqs, W1, W1T, b1, gammap, betap, W2T, b2, out, E);
}